// Round 3
// baseline (1553.133 us; speedup 1.0000x reference)
//
#include <hip/hip_runtime.h>
#include <hip/hip_bf16.h>
#include <stdint.h>

typedef __bf16 bf16;
typedef __bf16 bf16x8 __attribute__((ext_vector_type(8)));
typedef float f32x4 __attribute__((ext_vector_type(4)));

struct P22 { const void* p[22]; };
struct I22 { int n[22]; };

__device__ inline float bf2f(bf16 b) { return (float)b; }

// flag-dispatched scalar load: tensor may be bf16 (flag=0) or fp32 (flag=1)
__device__ inline float gld(const void* p, long i, int f32) {
    return f32 ? ((const float*)p)[i] : bf2f(((const bf16*)p)[i]);
}
// 8 contiguous elements -> bf16x8 (MFMA operand)
__device__ inline bf16x8 gld8(const void* p, long i, int f32) {
    bf16x8 r;
    if (f32) {
        const float* q = (const float*)p + i;
        f32x4 a = *(const f32x4*)q, b = *(const f32x4*)(q + 4);
        #pragma unroll
        for (int j = 0; j < 4; ++j) { r[j] = (bf16)a[j]; r[4 + j] = (bf16)b[j]; }
    } else {
        r = *reinterpret_cast<const bf16x8*>((const bf16*)p + i);
    }
    return r;
}
__device__ inline float fin(float v) { return isfinite(v) ? v : 0.f; }

// ---- per-tensor dtype detection: view data as bf16 pairs; fp32 data shows
// wild exponents in even (low-addr) slots, or even-all-zero for exact constants ----
__global__ void k_detect(P22 in, I22 sz, int* flags) {
    int t = blockIdx.x;
    if (t == 2 || t == 3) { if (threadIdx.x == 0) flags[t] = 0; return; }  // int tensors
    const unsigned short* u = (const unsigned short*)in.p[t];
    int pairs = sz.n[t] >> 1; if (pairs > 256) pairs = 256;
    int lane = threadIdx.x;  // blockDim = 64
    int insane = 0, evenNZ = 0, oddNZ = 0;
    for (int i = lane; i < pairs; i += 64) {
        unsigned short e = u[2 * i], o = u[2 * i + 1];
        int ee = (e >> 7) & 0xFF;            // bf16 exponent field
        if (e != 0) { evenNZ++; if (ee > 133 || ee < 108) insane++; }  // |v|>64 or <~2^-19
        if (o != 0) oddNZ++;
    }
    #pragma unroll
    for (int off = 1; off < 64; off <<= 1) {
        insane += __shfl_xor(insane, off, 64);
        evenNZ += __shfl_xor(evenNZ, off, 64);
        oddNZ  += __shfl_xor(oddNZ,  off, 64);
    }
    if (lane == 0) {
        int f32 = 0;
        if (insane * 4 > pairs) f32 = 1;              // wild even slots -> fp32
        else if (evenNZ == 0 && oddNZ > 0) f32 = 1;   // fp32 exact constants (e.g. 1.0)
        flags[t] = f32;                                // all-zero tensor: either view reads 0
    }
}

// ---- prep: Wcat = [W_sg | W_dg | W_du | W_su@W_gat] (bf16, 64x256), bcat fp32 ----
__global__ void k_prep(P22 in, const int* F, bf16* Wcat, float* bcat) {
    int j = threadIdx.x;            // 0..255 output column
    int sec = j >> 6, jc = j & 63;
    if (sec < 3) {
        int wi = sec == 0 ? 4 : (sec == 1 ? 6 : 12);
        const void* W = in.p[wi]; int fW = F[wi];
        for (int k = 0; k < 64; ++k) Wcat[k * 256 + j] = (bf16)gld(W, k * 64 + jc, fW);
        bcat[j] = gld(in.p[wi + 1], jc, F[wi + 1]);
    } else {
        const void* Wsu = in.p[10]; int f1 = F[10];
        const void* Wg  = in.p[14]; int f2 = F[14];
        for (int k = 0; k < 64; ++k) {
            float acc = 0.f;
            for (int t = 0; t < 64; ++t) acc += gld(Wsu, k * 64 + t, f1) * gld(Wg, t * 64 + jc, f2);
            Wcat[k * 256 + j] = (bf16)acc;
        }
        float acc = gld(in.p[15], jc, F[15]);  // b_gat
        for (int t = 0; t < 64; ++t) acc += gld(in.p[11], t, F[11]) * gld(Wg, t * 64 + jc, f2);
        bcat[j] = acc;
    }
}

// ---- node GEMM: NT[N][256] = node_feats @ Wcat + bcat  (bf16 out) ----
__global__ void __launch_bounds__(256) k_node_gemm(P22 in, const int* F, const bf16* Wcat,
                                                   const float* bcat, bf16* NT, int N) {
    int f0 = F[0];
    int lane = threadIdx.x & 63;
    int w = threadIdx.x >> 6;        // wave -> 64-col slab
    int col0 = w * 64, q = lane >> 4, li = lane & 15;
    bf16x8 bfr[4][2];
    #pragma unroll
    for (int t = 0; t < 4; ++t)
        #pragma unroll
        for (int h = 0; h < 2; ++h)
            #pragma unroll
            for (int j = 0; j < 8; ++j)
                bfr[t][h][j] = Wcat[(long)(h * 32 + q * 8 + j) * 256 + col0 + t * 16 + li];
    float bias[4];
    #pragma unroll
    for (int t = 0; t < 4; ++t) bias[t] = bcat[col0 + t * 16 + li];

    int ntiles = (N + 15) >> 4;
    for (int rt = blockIdx.x; rt < ntiles; rt += gridDim.x) {
        int row0 = rt * 16;
        int rload = min(row0 + li, N - 1);
        bf16x8 a0 = gld8(in.p[0], (long)rload * 64 + (q << 3), f0);
        bf16x8 a1 = gld8(in.p[0], (long)rload * 64 + 32 + (q << 3), f0);
        #pragma unroll
        for (int t = 0; t < 4; ++t) {
            f32x4 acc = {0.f, 0.f, 0.f, 0.f};
            acc = __builtin_amdgcn_mfma_f32_16x16x32_bf16(a0, bfr[t][0], acc, 0, 0, 0);
            acc = __builtin_amdgcn_mfma_f32_16x16x32_bf16(a1, bfr[t][1], acc, 0, 0, 0);
            int col = col0 + t * 16 + li;
            #pragma unroll
            for (int r = 0; r < 4; ++r) {
                int row = row0 + q * 4 + r;
                if (row < N) NT[(long)row * 256 + col] = (bf16)(acc[r] + bias[t]);
            }
        }
    }
}

// ---- el/er: [N][2] attention dots from feat = NT cols 192..255 ----
__global__ void k_elr(P22 in, const int* F, const bf16* NT, float* el, float* er, int N) {
    int lane = threadIdx.x & 63;
    int slot = threadIdx.x >> 6;
    int h = lane >> 5, dh = lane & 31;
    float al = gld(in.p[16], h * 32 + dh, F[16]);
    float ar = gld(in.p[17], h * 32 + dh, F[17]);
    for (int n = blockIdx.x * 4 + slot; n < N; n += gridDim.x * 4) {
        float f = bf2f(NT[(long)n * 256 + 192 + lane]);
        float pl = f * al, pr = f * ar;
        #pragma unroll
        for (int off = 1; off < 32; off <<= 1) {
            pl += __shfl_xor(pl, off, 64);
            pr += __shfl_xor(pr, off, 64);
        }
        if (dh == 0) { el[n * 2 + h] = pl; er[n * 2 + h] = pr; }
    }
}

// ---- edge phase 1: m in registers -> sigma/GAT atomics + BN-e stats (no m store) ----
__global__ void __launch_bounds__(256) k_edge_main(
    P22 in, const int* F, const bf16* NT, const float* el, const float* er,
    float* numer, float* denom, float* ssig, float* ssigh, float* bn_e_acc, int E) {
    int f_ef = F[1];
    int lane = threadIdx.x & 63;
    int w = threadIdx.x >> 6;
    int q = lane >> 4, li = lane & 15;
    const int* srcp = (const int*)in.p[2];
    const int* dstp = (const int*)in.p[3];

    bf16x8 bfrag[4][2];
    #pragma unroll
    for (int t = 0; t < 4; ++t)
        #pragma unroll
        for (int h = 0; h < 2; ++h)
            #pragma unroll
            for (int j = 0; j < 8; ++j)
                bfrag[t][h][j] = (bf16)gld(in.p[8], (long)(h * 32 + q * 8 + j) * 64 + t * 16 + li, F[8]);
    float bias[4];
    #pragma unroll
    for (int t = 0; t < 4; ++t) bias[t] = gld(in.p[9], t * 16 + li, F[9]);

    float as[4] = {0.f, 0.f, 0.f, 0.f}, aq[4] = {0.f, 0.f, 0.f, 0.f};

    int ntiles = E >> 4;   // E divisible by 16
    for (int et = blockIdx.x * 4 + w; et < ntiles; et += gridDim.x * 4) {
        int e0 = et * 16;
        bf16x8 a0 = gld8(in.p[1], (long)(e0 + li) * 64 + (q << 3), f_ef);
        bf16x8 a1 = gld8(in.p[1], (long)(e0 + li) * 64 + 32 + (q << 3), f_ef);
        f32x4 acc[4];
        #pragma unroll
        for (int t = 0; t < 4; ++t) {
            f32x4 c = {0.f, 0.f, 0.f, 0.f};
            c = __builtin_amdgcn_mfma_f32_16x16x32_bf16(a0, bfrag[t][0], c, 0, 0, 0);
            c = __builtin_amdgcn_mfma_f32_16x16x32_bf16(a1, bfrag[t][1], c, 0, 0, 0);
            acc[t] = c;
        }
        #pragma unroll
        for (int r = 0; r < 4; ++r) {
            int e = e0 + q * 4 + r;           // C/D rows: (lane>>4)*4 + r
            int si = srcp[e], di = dstp[e];
            const bf16* srow = NT + (long)si * 256;
            const bf16* drow = NT + (long)di * 256;
            // softmax without segment-max (shift-invariant; logits O(1))
            float2 l2 = *(const float2*)(el + (long)si * 2);
            float2 r2 = *(const float2*)(er + (long)di * 2);
            float lg0 = l2.x + r2.x; lg0 = lg0 > 0.f ? lg0 : 0.2f * lg0;
            float lg1 = l2.y + r2.y; lg1 = lg1 > 0.f ? lg1 : 0.2f * lg1;
            lg0 = fminf(fmaxf(lg0, -30.f), 30.f);
            lg1 = fminf(fmaxf(lg1, -30.f), 30.f);
            float ex0 = __expf(lg0), ex1 = __expf(lg1);
            if (li < 2) atomicAdd(denom + (long)di * 2 + li, li == 0 ? ex0 : ex1);
            #pragma unroll
            for (int t = 0; t < 4; ++t) {
                int col = t * 16 + li;
                float mv = acc[t][r] + bias[t] + bf2f(srow[col]) + bf2f(drow[64 + col]);
                float bh = bf2f(srow[128 + col]);
                float ft = bf2f(srow[192 + col]);
                float sg = 1.f / (1.f + __expf(-mv));
                atomicAdd(ssig  + (long)di * 64 + col, sg);
                atomicAdd(ssigh + (long)di * 64 + col, bh * sg);
                atomicAdd(numer + (long)di * 64 + col, ft * (col < 32 ? ex0 : ex1));
                as[t] += mv; aq[t] += mv * mv;
            }
        }
    }
    __shared__ float red_s[256], red_q[256];
    #pragma unroll
    for (int t = 0; t < 4; ++t) {
        float s = as[t], qq = aq[t];
        s += __shfl_xor(s, 16, 64); s += __shfl_xor(s, 32, 64);
        qq += __shfl_xor(qq, 16, 64); qq += __shfl_xor(qq, 32, 64);
        if (q == 0) { red_s[w * 64 + t * 16 + li] = s; red_q[w * 64 + t * 16 + li] = qq; }
    }
    __syncthreads();
    if (threadIdx.x < 64) {
        int c = threadIdx.x;
        float s  = red_s[c] + red_s[64 + c] + red_s[128 + c] + red_s[192 + c];
        float qq = red_q[c] + red_q[64 + c] + red_q[128 + c] + red_q[192 + c];
        atomicAdd(bn_e_acc + c, s);
        atomicAdd(bn_e_acc + 64 + c, qq);
    }
}

__device__ inline float node_preval(const float* numer, const float* denom,
                                    const float* ssig, const float* ssigh,
                                    float bg, int n, int c) {
    float ss = ssig[(long)n * 64 + c];
    float sh = ssigh[(long)n * 64 + c];
    float hagg = sh / (ss + 1e-6f);
    float dn = denom[(long)n * 2 + (c >> 5)];
    float nm = numer[(long)n * 64 + c];
    float gat = dn > 0.f ? nm / dn : 0.f;   // zero in-degree safety
    return hagg + gat + bg;
}

__global__ void k_node_stats(P22 in, const int* F, const float* numer, const float* denom,
                             const float* ssig, const float* ssigh, float* bn_n_acc, int N) {
    int c = threadIdx.x & 63;
    int slot = threadIdx.x >> 6;
    float bg = gld(in.p[15], c, F[15]);
    float s = 0.f, qq = 0.f;
    for (int n = blockIdx.x * 4 + slot; n < N; n += gridDim.x * 4) {
        float v = node_preval(numer, denom, ssig, ssigh, bg, n, c);
        s += v; qq += v * v;
    }
    __shared__ float red_s[256], red_q[256];
    red_s[threadIdx.x] = s; red_q[threadIdx.x] = qq;
    __syncthreads();
    if (threadIdx.x < 64) {
        float ts = red_s[c] + red_s[64 + c] + red_s[128 + c] + red_s[192 + c];
        float tq = red_q[c] + red_q[64 + c] + red_q[128 + c] + red_q[192 + c];
        atomicAdd(bn_n_acc + c, ts);
        atomicAdd(bn_n_acc + 64 + c, tq);
    }
}

// ---- x output: x = node + silu(BN_n(v)) ----
__global__ void k_x_out(P22 in, const int* F, const float* numer, const float* denom,
                        const float* ssig, const float* ssigh,
                        const float* acc, void* d_out, int N) {
    int f_out = F[0];
    int c = threadIdx.x & 63;
    int slot = threadIdx.x >> 6;
    float bg = gld(in.p[15], c, F[15]);
    float inv = 1.f / (float)N;
    float mean = acc[c] * inv;
    float var = fmaxf(acc[64 + c] * inv - mean * mean, 0.f);
    float rstd = rsqrtf(var + 1e-5f);
    float ga = gld(in.p[18], c, F[18]), be = gld(in.p[19], c, F[19]);
    for (int n = blockIdx.x * 4 + slot; n < N; n += gridDim.x * 4) {
        float v = node_preval(numer, denom, ssig, ssigh, bg, n, c);
        float t = (v - mean) * rstd * ga + be;
        float sl = t / (1.f + __expf(-t));
        float x = fin(gld(in.p[0], (long)n * 64 + c, F[0]) + sl);
        if (f_out) ((float*)d_out)[(long)n * 64 + c] = x;
        else       ((bf16*)d_out)[(long)n * 64 + c] = (bf16)x;
    }
}

// ---- edge phase 2: recompute m, y = ef + silu(BN_e(m)) ----
__global__ void __launch_bounds__(256) k_edge_y(
    P22 in, const int* F, const bf16* NT, const float* bn_e_acc,
    void* d_out, int N, int E) {
    int f_ef = F[1], f_out = F[0];
    int lane = threadIdx.x & 63;
    int w = threadIdx.x >> 6;
    int q = lane >> 4, li = lane & 15;
    const int* srcp = (const int*)in.p[2];
    const int* dstp = (const int*)in.p[3];

    bf16x8 bfrag[4][2];
    #pragma unroll
    for (int t = 0; t < 4; ++t)
        #pragma unroll
        for (int h = 0; h < 2; ++h)
            #pragma unroll
            for (int j = 0; j < 8; ++j)
                bfrag[t][h][j] = (bf16)gld(in.p[8], (long)(h * 32 + q * 8 + j) * 64 + t * 16 + li, F[8]);
    float bias[4], mean[4], rstd[4], ga[4], be[4];
    float invE = 1.f / (float)E;
    #pragma unroll
    for (int t = 0; t < 4; ++t) {
        int c = t * 16 + li;
        bias[t] = gld(in.p[9], c, F[9]);
        float mn = bn_e_acc[c] * invE;
        float vr = fmaxf(bn_e_acc[64 + c] * invE - mn * mn, 0.f);
        mean[t] = mn; rstd[t] = rsqrtf(vr + 1e-5f);
        ga[t] = gld(in.p[20], c, F[20]); be[t] = gld(in.p[21], c, F[21]);
    }
    char* yb = (char*)d_out + (size_t)N * 64 * (f_out ? 4 : 2);

    int ntiles = E >> 4;
    for (int et = blockIdx.x * 4 + w; et < ntiles; et += gridDim.x * 4) {
        int e0 = et * 16;
        bf16x8 a0 = gld8(in.p[1], (long)(e0 + li) * 64 + (q << 3), f_ef);
        bf16x8 a1 = gld8(in.p[1], (long)(e0 + li) * 64 + 32 + (q << 3), f_ef);
        f32x4 acc[4];
        #pragma unroll
        for (int t = 0; t < 4; ++t) {
            f32x4 c = {0.f, 0.f, 0.f, 0.f};
            c = __builtin_amdgcn_mfma_f32_16x16x32_bf16(a0, bfrag[t][0], c, 0, 0, 0);
            c = __builtin_amdgcn_mfma_f32_16x16x32_bf16(a1, bfrag[t][1], c, 0, 0, 0);
            acc[t] = c;
        }
        #pragma unroll
        for (int r = 0; r < 4; ++r) {
            int e = e0 + q * 4 + r;
            int si = srcp[e], di = dstp[e];
            const bf16* srow = NT + (long)si * 256;
            const bf16* drow = NT + (long)di * 256;
            #pragma unroll
            for (int t = 0; t < 4; ++t) {
                int col = t * 16 + li;
                float mv = acc[t][r] + bias[t] + bf2f(srow[col]) + bf2f(drow[64 + col]);
                float tt = (mv - mean[t]) * rstd[t] * ga[t] + be[t];
                float sl = tt / (1.f + __expf(-tt));
                float ev = gld(in.p[1], (long)e * 64 + col, f_ef);
                float y = fin(ev + sl);
                if (f_out) ((float*)yb)[(long)e * 64 + col] = y;
                else       ((bf16*)yb)[(long)e * 64 + col] = (bf16)y;
            }
        }
    }
}

extern "C" void kernel_launch(void* const* d_in, const int* in_sizes, int n_in,
                              void* d_out, int out_size, void* d_ws, size_t ws_size,
                              hipStream_t stream) {
    P22 p; I22 sz;
    for (int i = 0; i < 22; ++i) { p.p[i] = d_in[i]; sz.n[i] = in_sizes[i]; }
    const int N = in_sizes[0] / 64;
    const int E = in_sizes[2];

    char* ws = (char*)d_ws;
    size_t off = 0;
    auto alloc = [&](size_t bytes) -> void* {
        void* ptr = ws + off;
        off = (off + bytes + 255) & ~(size_t)255;
        return ptr;
    };
    int*   flags = (int*)  alloc(22 * 4);
    bf16*  NT    = (bf16*) alloc((size_t)N * 256 * 2);   // [e_src|e_dst|Bh|feat] bf16
    float* el    = (float*)alloc((size_t)N * 2 * 4);
    float* er    = (float*)alloc((size_t)N * 2 * 4);
    bf16*  Wcat  = (bf16*) alloc(64 * 256 * 2);
    float* bcat  = (float*)alloc(256 * 4);
    char* zbase = ws + off;
    float* numer = (float*)alloc((size_t)N * 64 * 4);
    float* denom = (float*)alloc((size_t)N * 2 * 4);
    float* ssig  = (float*)alloc((size_t)N * 64 * 4);
    float* ssigh = (float*)alloc((size_t)N * 64 * 4);
    float* bn_e_acc = (float*)alloc(128 * 4);
    float* bn_n_acc = (float*)alloc(128 * 4);
    size_t zbytes = (size_t)((ws + off) - zbase);
    hipMemsetAsync(zbase, 0, zbytes, stream);

    hipLaunchKernelGGL(k_detect, dim3(22), dim3(64), 0, stream, p, sz, flags);
    hipLaunchKernelGGL(k_prep, dim3(1), dim3(256), 0, stream, p, flags, Wcat, bcat);
    hipLaunchKernelGGL(k_node_gemm, dim3(800), dim3(256), 0, stream, p, flags, Wcat, bcat, NT, N);
    hipLaunchKernelGGL(k_elr, dim3(512), dim3(256), 0, stream, p, flags, NT, el, er, N);
    hipLaunchKernelGGL(k_edge_main, dim3(1024), dim3(256), 0, stream,
                       p, flags, NT, el, er, numer, denom, ssig, ssigh, bn_e_acc, E);
    hipLaunchKernelGGL(k_node_stats, dim3(256), dim3(256), 0, stream,
                       p, flags, numer, denom, ssig, ssigh, bn_n_acc, N);
    hipLaunchKernelGGL(k_x_out, dim3(512), dim3(256), 0, stream,
                       p, flags, numer, denom, ssig, ssigh, bn_n_acc, d_out, N);
    hipLaunchKernelGGL(k_edge_y, dim3(1024), dim3(256), 0, stream,
                       p, flags, NT, bn_e_acc, d_out, N, E);
}